// Round 12
// baseline (98.086 us; speedup 1.0000x reference)
//
#include <hip/hip_runtime.h>
#include <hip/hip_bf16.h>

#define NB 4
#define NH 12
#define SEQ 4096
#define DIM 64
#define LOG2E 1.4426950408889634f

typedef __attribute__((ext_vector_type(8))) short short8;
typedef __attribute__((ext_vector_type(4))) float f32x4;
typedef __attribute__((ext_vector_type(2))) unsigned int u32x2;

static __device__ __forceinline__ unsigned int pk2(float a, float b) {
    float2 t; t.x = a; t.y = b;
    union { __hip_bfloat162 h; unsigned int u; } x;
    x.h = __float22bfloat162_rn(t);
    return x.u;
}
static __device__ __forceinline__ short8 mk8(unsigned int a, unsigned int b,
                                             unsigned int c, unsigned int d) {
    union { unsigned int u[4]; short8 s; } x;
    x.u[0] = a; x.u[1] = b; x.u[2] = c; x.u[3] = d;
    return x.s;
}

__global__ __launch_bounds__(512, 4)
void blk_attn(const float* __restrict__ Q, const float* __restrict__ K,
              const float* __restrict__ V, const float* __restrict__ M,
              float* __restrict__ O) {
    int bid = blockIdx.x;
    bid = (bid & 7) * 192 + (bid >> 3);   // XCD swizzle (1536 % 8 == 0)

    const int j  = bid & 31;
    const int bh = bid >> 5;
    const int b  = bh / NH;

    const size_t base = (size_t)bh * SEQ * DIM;
    const float* Kp = K + base;
    const float* Vp = V + base;

    const int tid  = threadIdx.x;
    const int w    = tid >> 6;      // wave 0..7, owns queries [16w, 16w+16)
    const int lane = tid & 63;
    const int lo   = lane & 15;
    const int hi   = lane >> 4;

    // two 256-key windows: A = [128j-128, +256), B = [128j, +256)
    const float wtA = (j == 0)  ? 0.f : ((j == 31) ? 1.f : 0.5f);
    const float wtB = (j == 31) ? 0.f : ((j == 0)  ? 1.f : 0.5f);

    // ---- LDS: exactly 80 KB -> 2 independent blocks/CU ----
    __shared__ __align__(16) unsigned char smem[81920];
    auto Ks = (unsigned short (*)[64])(smem);            // [256][64]: K[key][d ^ 8*(key&7)]
    auto Vt = (unsigned short (*)[256])(smem + 32768);   // [64][256]: V^T[d][k ^ 8*((d^(d>>2))&7)]
    auto Pw = (unsigned int (*)[16][32])(smem + 65536);  // [8 waves][16 q][32 dw]

    // ---- Q fragments, scaled by log2e/8 (live across both windows) ----
    short8 qa[2];
    {
        const float qs = 0.125f * LOG2E;
        const float* qr = Q + base + (size_t)(128 * j + 16 * w + lo) * DIM + hi * 8;
        #pragma unroll
        for (int s = 0; s < 2; ++s) {
            f32x4 a = *reinterpret_cast<const f32x4*>(qr + 32 * s);
            f32x4 c = *reinterpret_cast<const f32x4*>(qr + 32 * s + 4);
            qa[s] = mk8(pk2(a[0] * qs, a[1] * qs), pk2(a[2] * qs, a[3] * qs),
                        pk2(c[0] * qs, c[1] * qs), pk2(c[2] * qs, c[3] * qs));
        }
    }

    f32x4 fin[4];
    #pragma unroll
    for (int dt = 0; dt < 4; ++dt) { fin[dt][0]=0.f; fin[dt][1]=0.f; fin[dt][2]=0.f; fin[dt][3]=0.f; }

    const int c8 = lane & 7, r8 = lane >> 3;
    const int quad = lane & 3, colq = lane >> 2;
    const int kswz = 8 * (lo & 7);
    const int pswz = 4 * (lo & 7);

    #pragma unroll
    for (int wi = 0; wi < 2; ++wi) {
        const float wt = wi ? wtB : wtA;
        if (wt == 0.f) continue;                 // block-uniform (j uniform)
        const int kw = 128 * j - 128 + 128 * wi; // window base, in [0, 3840]

        if (wi == 1 && wtA != 0.f) __syncthreads();   // prior window's reads done

        // ---- stage K: 256 rows, b128 conflict-free writes ----
        #pragma unroll
        for (int it = 0; it < 4; ++it) {
            const int row = 32 * w + 8 * it + r8;        // row & 7 == r8
            const float* kp = Kp + (size_t)(kw + row) * DIM + 8 * c8;
            f32x4 a = *reinterpret_cast<const f32x4*>(kp);
            f32x4 c = *reinterpret_cast<const f32x4*>(kp + 4);
            *reinterpret_cast<short8*>(&Ks[row][(8 * c8) ^ (8 * r8)]) =
                mk8(pk2(a[0], a[1]), pk2(a[2], a[3]), pk2(c[0], c[1]), pk2(c[2], c[3]));
        }
        // ---- stage V^T: 4x4 register transpose ----
        #pragma unroll
        for (int it = 0; it < 2; ++it) {
            const int kg = 2 * w + it;                   // 0..15
            const int k0 = 16 * kg + 4 * quad;
            f32x4 vr[4];
            #pragma unroll
            for (int kk = 0; kk < 4; ++kk)
                vr[kk] = *reinterpret_cast<const f32x4*>(
                    Vp + (size_t)(kw + k0 + kk) * DIM + 4 * colq);
            #pragma unroll
            for (int i = 0; i < 4; ++i) {
                const int d  = 4 * colq + i;
                const int gd = (d ^ (d >> 2)) & 7;
                u32x2 o;
                o[0] = pk2(vr[0][i], vr[1][i]);
                o[1] = pk2(vr[2][i], vr[3][i]);
                *reinterpret_cast<u32x2*>(&Vt[d][k0 ^ (8 * gd)]) = o;
            }
        }
        __syncthreads();

        // ---- QK^T swapped: st[l] = S[key=16l+4hi+r][q=lo] ----
        f32x4 st[16];
        #pragma unroll
        for (int l = 0; l < 16; ++l) { st[l][0]=0.f; st[l][1]=0.f; st[l][2]=0.f; st[l][3]=0.f; }
        __builtin_amdgcn_s_setprio(1);
        #pragma unroll
        for (int s = 0; s < 2; ++s)
            #pragma unroll
            for (int l = 0; l < 16; ++l) {
                short8 kf = *reinterpret_cast<const short8*>(
                    &Ks[16 * l + lo][(32 * s + 8 * hi) ^ kswz]);
                st[l] = __builtin_amdgcn_mfma_f32_16x16x32_bf16(kf, qa[s], st[l], 0, 0, 0);
            }
        __builtin_amdgcn_s_setprio(0);

        // ---- mask (global, L2/L3-resident; pre-scaled by log2e) ----
        const float* Mq = M + (size_t)b * SEQ + kw;
        #pragma unroll
        for (int l = 0; l < 16; ++l) {
            f32x4 mv = *reinterpret_cast<const f32x4*>(Mq + 16 * l + 4 * hi);
            #pragma unroll
            for (int r = 0; r < 4; ++r) st[l][r] = fmaf(mv[r], LOG2E, st[l][r]);
        }

        // ---- exact softmax over this window (q = lo, lane-local) ----
        float mx = st[0][0];
        #pragma unroll
        for (int l = 0; l < 16; ++l)
            #pragma unroll
            for (int r = 0; r < 4; ++r) mx = fmaxf(mx, st[l][r]);
        mx = fmaxf(mx, __shfl_xor(mx, 16));
        mx = fmaxf(mx, __shfl_xor(mx, 32));
        #pragma unroll
        for (int l = 0; l < 16; ++l)
            #pragma unroll
            for (int r = 0; r < 4; ++r) st[l][r] = exp2f(st[l][r] - mx);
        float S = 0.f;
        #pragma unroll
        for (int l = 0; l < 16; ++l)
            S += (st[l][0] + st[l][1]) + (st[l][2] + st[l][3]);
        S += __shfl_xor(S, 16); S += __shfl_xor(S, 32);

        // ---- PV swapped (O^T): 8 kq of 32 keys, single-buffer Pw (in-order DS) ----
        f32x4 acc[4];
        #pragma unroll
        for (int dt = 0; dt < 4; ++dt) { acc[dt][0]=0.f; acc[dt][1]=0.f; acc[dt][2]=0.f; acc[dt][3]=0.f; }
        #pragma unroll
        for (int kq = 0; kq < 8; ++kq) {
            const int pp = 16 * (kq & 1);
            u32x2 w0v, w1v;
            w0v[0] = pk2(st[2 * kq][0],     st[2 * kq][1]);
            w0v[1] = pk2(st[2 * kq][2],     st[2 * kq][3]);
            w1v[0] = pk2(st[2 * kq + 1][0], st[2 * kq + 1][1]);
            w1v[1] = pk2(st[2 * kq + 1][2], st[2 * kq + 1][3]);
            *reinterpret_cast<u32x2*>(&Pw[w][lo][(pp + 2 * hi)     ^ pswz]) = w0v;
            *reinterpret_cast<u32x2*>(&Pw[w][lo][(pp + 8 + 2 * hi) ^ pswz]) = w1v;
            short8 pf = *reinterpret_cast<const short8*>(&Pw[w][lo][(pp + 4 * hi) ^ pswz]);
            __builtin_amdgcn_s_setprio(1);
            #pragma unroll
            for (int dt = 0; dt < 4; ++dt) {
                const int d  = 16 * dt + lo;
                const int gd = (d ^ (d >> 2)) & 7;
                short8 vf = *reinterpret_cast<const short8*>(
                    &Vt[d][(32 * kq + 8 * hi) ^ (8 * gd)]);
                acc[dt] = __builtin_amdgcn_mfma_f32_16x16x32_bf16(vf, pf, acc[dt], 0, 0, 0);
            }
            __builtin_amdgcn_s_setprio(0);
        }

        // ---- weighted accumulate (lane-local coef, q = lo) ----
        const float coef = wt / S;
        #pragma unroll
        for (int dt = 0; dt < 4; ++dt)
            #pragma unroll
            for (int r = 0; r < 4; ++r) fin[dt][r] = fmaf(coef, acc[dt][r], fin[dt][r]);
    }

    // ---- store O^T-layout rows: O[128j+16w+lo][16dt+4hi .. +4) ----
    float* Opr = O + base + (size_t)(128 * j + 16 * w + lo) * DIM + 4 * hi;
    #pragma unroll
    for (int dt = 0; dt < 4; ++dt)
        *reinterpret_cast<f32x4*>(Opr + 16 * dt) = fin[dt];
}

extern "C" void kernel_launch(void* const* d_in, const int* in_sizes, int n_in,
                              void* d_out, int out_size, void* d_ws, size_t ws_size,
                              hipStream_t stream) {
    const float* Q = (const float*)d_in[0];
    const float* K = (const float*)d_in[1];
    const float* V = (const float*)d_in[2];
    const float* M = (const float*)d_in[3];
    float* O = (float*)d_out;
    blk_attn<<<dim3(NB * NH * (SEQ / 128)), dim3(512), 0, stream>>>(Q, K, V, M, O);
}